// Round 1
// baseline (868.341 us; speedup 1.0000x reference)
//
#include <hip/hip_runtime.h>
#include <hip/hip_bf16.h>

#define N_NODES 100000
#define N_EDGES 800000
#define DD 128
#define NBLK 782          // ceil(N_NODES / 128)
#define NSCAN1 391        // ceil(N_NODES / 256)
#define EPSV 1e-5f

typedef short bf16x8 __attribute__((ext_vector_type(8)));
typedef short bf16x2 __attribute__((ext_vector_type(2)));
typedef float f32x4 __attribute__((ext_vector_type(4)));
typedef float f32x2 __attribute__((ext_vector_type(2)));

__device__ __forceinline__ short f2bf(float f) {
    unsigned u = __float_as_uint(f);
    unsigned r = (u + 0x7fffu + ((u >> 16) & 1u)) >> 16;  // RNE
    return (short)r;
}

// ---------------- CSR build ----------------
__global__ void k_count(const int* __restrict__ dst, int* __restrict__ cnt) {
    int e = blockIdx.x * 256 + threadIdx.x;
    if (e < N_EDGES) atomicAdd(&cnt[dst[e]], 1);
}

__global__ void k_scan1(const int* __restrict__ cnt, int* __restrict__ off,
                        int* __restrict__ bsums) {
    __shared__ int s[256];
    int i = blockIdx.x * 256 + threadIdx.x;
    int t = threadIdx.x;
    s[t] = (i < N_NODES) ? cnt[i] : 0;
    __syncthreads();
    for (int d = 1; d < 256; d <<= 1) {
        int x = 0;
        if (t >= d) x = s[t - d];
        __syncthreads();
        s[t] += x;
        __syncthreads();
    }
    if (i < N_NODES) off[i + 1] = s[t];
    if (t == 255) bsums[blockIdx.x] = s[255];
}

__global__ void k_scan2(int* __restrict__ bsums) {
    __shared__ int s[512];
    int t = threadIdx.x;
    s[t] = (t < NSCAN1) ? bsums[t] : 0;
    __syncthreads();
    for (int d = 1; d < 512; d <<= 1) {
        int x = 0;
        if (t >= d) x = s[t - d];
        __syncthreads();
        s[t] += x;
        __syncthreads();
    }
    if (t < NSCAN1) bsums[t] = s[t];   // inclusive
}

__global__ void k_scan3(int* __restrict__ off, const int* __restrict__ bsums) {
    int i = blockIdx.x * 256 + threadIdx.x;
    int add = (blockIdx.x > 0) ? bsums[blockIdx.x - 1] : 0;
    if (i < N_NODES) off[i + 1] += add;
    if (i == 0) off[0] = 0;
}

__global__ void k_fill(const int* __restrict__ src, const int* __restrict__ dst,
                       const int* __restrict__ off, int* __restrict__ cur,
                       int* __restrict__ elist) {
    int e = blockIdx.x * 256 + threadIdx.x;
    if (e < N_EDGES) {
        int d = dst[e];
        int p = atomicAdd(&cur[d], 1);
        elist[off[d] + p] = src[e];
    }
}

// ---------------- weights fp32 -> bf16 ----------------
__global__ void k_wconv(const float* __restrict__ wl, const float* __restrict__ wr,
                        short* __restrict__ wbf) {
    int i = blockIdx.x * 256 + threadIdx.x;
    if (i < 3 * DD * DD) {
        wbf[i] = f2bf(wl[i]);
        wbf[3 * DD * DD + i] = f2bf(wr[i]);
    }
}

// ---------------- fused SAGE layer ----------------
// block: 512 threads (8 waves), 128 nodes. LDS: two 128x128 bf16 tiles (64KB).
template <bool ELU_ON, bool AFF_ON>
__global__ __launch_bounds__(512) void k_sage(
    const float* __restrict__ xin, const float* __restrict__ aff,
    const int* __restrict__ off, const int* __restrict__ elist,
    const short* __restrict__ wl, const short* __restrict__ wr,
    const float* __restrict__ bias,
    float* __restrict__ hout, float* __restrict__ partials)
{
    __shared__ short agg_t[128 * 128];
    __shared__ short x_t[128 * 128];
    const int tid = threadIdx.x;
    const int w = tid >> 6;
    const int l = tid & 63;
    const int base = blockIdx.x * 128;

    float a0 = 1.f, a1 = 1.f, c0 = 0.f, c1 = 0.f;
    if (AFF_ON) {
        a0 = aff[2 * l];       a1 = aff[2 * l + 1];
        c0 = aff[128 + 2 * l]; c1 = aff[128 + 2 * l + 1];
    }

    // ---- gather phase: wave w owns rows w*16 .. w*16+15 ----
    for (int i = 0; i < 16; ++i) {
        int m = w * 16 + i;
        int g = base + m;
        float s0 = 0.f, s1 = 0.f, r0 = 0.f, r1 = 0.f;
        if (g < N_NODES) {
            int e0 = off[g], e1 = off[g + 1];
            for (int e = e0; e < e1; ++e) {
                int sn = elist[e];
                f32x2 v = *(const f32x2*)(xin + (size_t)sn * DD + 2 * l);
                s0 += v.x; s1 += v.y;
            }
            int deg = e1 - e0;
            if (deg > 0) {
                float inv = 1.f / (float)deg;
                s0 *= inv; s1 *= inv;
                if (AFF_ON) { s0 = a0 * s0 + c0; s1 = a1 * s1 + c1; }
            }
            f32x2 xv = *(const f32x2*)(xin + (size_t)g * DD + 2 * l);
            r0 = xv.x; r1 = xv.y;
            if (AFF_ON) { r0 = a0 * r0 + c0; r1 = a1 * r1 + c1; }
        }
        int ei = m * DD + ((2 * l) ^ ((m & 7) << 3));   // XOR swizzle (G4)
        bf16x2 ta; ta[0] = f2bf(s0); ta[1] = f2bf(s1);
        bf16x2 tx; tx[0] = f2bf(r0); tx[1] = f2bf(r1);
        *(bf16x2*)&agg_t[ei] = ta;
        *(bf16x2*)&x_t[ei]   = tx;
    }
    __syncthreads();

    // ---- MFMA phase: wave w computes rows w*16..+15 x 128 cols ----
    f32x4 acc[8];
#pragma unroll
    for (int nb = 0; nb < 8; ++nb) acc[nb] = f32x4{0.f, 0.f, 0.f, 0.f};
    const int mrow = w * 16 + (l & 15);
    const int kg = (l >> 4) * 8;
    const int nloc = l & 15;
#pragma unroll
    for (int ks = 0; ks < 4; ++ks) {
        int kk = ks * 32 + kg;
        int sw = kk ^ ((mrow & 7) << 3);
        bf16x8 aa = *(const bf16x8*)&agg_t[mrow * DD + sw];
        bf16x8 ax = *(const bf16x8*)&x_t[mrow * DD + sw];
#pragma unroll
        for (int nb = 0; nb < 8; ++nb) {
            int n = nb * 16 + nloc;
            bf16x8 bl = *(const bf16x8*)&wl[n * DD + kk];
            bf16x8 br = *(const bf16x8*)&wr[n * DD + kk];
            acc[nb] = __builtin_amdgcn_mfma_f32_16x16x32_bf16(aa, bl, acc[nb], 0, 0, 0);
            acc[nb] = __builtin_amdgcn_mfma_f32_16x16x32_bf16(ax, br, acc[nb], 0, 0, 0);
        }
    }

    // ---- epilogue: bias, ELU, store, column stats ----
    float colS[8], colQ[8];
#pragma unroll
    for (int nb = 0; nb < 8; ++nb) {
        int n = nb * 16 + nloc;
        float bv = bias[n];
        float cs = 0.f, cq = 0.f;
#pragma unroll
        for (int r = 0; r < 4; ++r) {
            int m = w * 16 + (l >> 4) * 4 + r;
            int g = base + m;
            float hv = acc[nb][r] + bv;
            if (ELU_ON) hv = hv > 0.f ? hv : expm1f(hv);
            bool valid = g < N_NODES;
            if (valid) hout[(size_t)g * DD + n] = hv;
            float hm = valid ? hv : 0.f;
            cs += hm;
            cq += hm * hm;
        }
        colS[nb] = cs; colQ[nb] = cq;
    }
#pragma unroll
    for (int nb = 0; nb < 8; ++nb) {
        colS[nb] += __shfl_xor(colS[nb], 16, 64);
        colS[nb] += __shfl_xor(colS[nb], 32, 64);
        colQ[nb] += __shfl_xor(colQ[nb], 16, 64);
        colQ[nb] += __shfl_xor(colQ[nb], 32, 64);
    }
    __syncthreads();                      // all LDS tile reads done
    float* sl = (float*)x_t;              // reuse: 8 waves * 256 floats
    if (l < 16) {
#pragma unroll
        for (int nb = 0; nb < 8; ++nb) {
            sl[w * 256 + nb * 16 + l]       = colS[nb];
            sl[w * 256 + 128 + nb * 16 + l] = colQ[nb];
        }
    }
    __syncthreads();
    if (tid < 256) {
        float t = 0.f;
#pragma unroll
        for (int w2 = 0; w2 < 8; ++w2) t += sl[w2 * 256 + tid];
        partials[blockIdx.x * 256 + tid] = t;
    }
}

// ---------------- BN stats -> affine ----------------
__global__ void k_reduce(const float* __restrict__ partials,
                         const float* __restrict__ gamma, const float* __restrict__ beta,
                         float* __restrict__ aff) {
    int f = blockIdx.x;     // 0..127
    int t = threadIdx.x;    // 256
    float s = 0.f, q = 0.f;
    for (int i = t; i < NBLK; i += 256) {
        s += partials[i * 256 + f];
        q += partials[i * 256 + 128 + f];
    }
    __shared__ float rs[256], rq[256];
    rs[t] = s; rq[t] = q;
    __syncthreads();
    for (int d = 128; d > 0; d >>= 1) {
        if (t < d) { rs[t] += rs[t + d]; rq[t] += rq[t + d]; }
        __syncthreads();
    }
    if (t == 0) {
        float mean = rs[0] / (float)N_NODES;
        float var = rq[0] / (float)N_NODES - mean * mean;
        float a = gamma[f] * rsqrtf(var + EPSV);
        aff[f] = a;
        aff[128 + f] = beta[f] - mean * a;
    }
}

// ---------------- final BN apply (in place) ----------------
__global__ void k_apply(float* __restrict__ out, const float* __restrict__ aff) {
    int i = blockIdx.x * 256 + threadIdx.x;  // float4 index
    if (i < N_NODES * DD / 4) {
        f32x4 v = *(f32x4*)(out + (size_t)i * 4);
        int f = (i * 4) & 127;
        f32x4 a = *(const f32x4*)(aff + f);
        f32x4 c = *(const f32x4*)(aff + 128 + f);
        v = a * v + c;
        *(f32x4*)(out + (size_t)i * 4) = v;
    }
}

extern "C" void kernel_launch(void* const* d_in, const int* in_sizes, int n_in,
                              void* d_out, int out_size, void* d_ws, size_t ws_size,
                              hipStream_t stream) {
    const float* x     = (const float*)d_in[0];
    const int*   ei    = (const int*)d_in[1];
    const float* Wl    = (const float*)d_in[2];
    const float* Wr    = (const float*)d_in[3];
    const float* b     = (const float*)d_in[4];
    const float* gamma = (const float*)d_in[5];
    const float* beta  = (const float*)d_in[6];
    float* out = (float*)d_out;

    char* ws = (char*)d_ws;
    int*   off      = (int*)(ws + 0);              // (N+1) ints
    int*   cnt      = (int*)(ws + 400128);         // N ints (also cursor)
    int*   elist    = (int*)(ws + 800256);         // E ints
    int*   bsums    = (int*)(ws + 4000256);        // 512 ints
    float* partials = (float*)(ws + 4002304);      // NBLK*256 floats
    float* affine   = (float*)(ws + 4803328);      // 256 floats
    short* wbf      = (short*)(ws + 4804352);      // 2*3*128*128 bf16
    float* hbuf     = (float*)(ws + 5197824);      // N*D floats

    const int* src = ei;
    const int* dst = ei + N_EDGES;
    short* wbl = wbf;
    short* wbr = wbf + 3 * DD * DD;

    // CSR build
    hipMemsetAsync(cnt, 0, N_NODES * sizeof(int), stream);
    k_count<<<(N_EDGES + 255) / 256, 256, 0, stream>>>(dst, cnt);
    k_scan1<<<NSCAN1, 256, 0, stream>>>(cnt, off, bsums);
    k_scan2<<<1, 512, 0, stream>>>(bsums);
    k_scan3<<<NSCAN1, 256, 0, stream>>>(off, bsums);
    hipMemsetAsync(cnt, 0, N_NODES * sizeof(int), stream);
    k_fill<<<(N_EDGES + 255) / 256, 256, 0, stream>>>(src, dst, off, cnt, elist);

    // weights to bf16
    k_wconv<<<(3 * DD * DD + 255) / 256, 256, 0, stream>>>(Wl, Wr, wbf);

    // layer 0: x -> h0 (in d_out), ELU, no input affine
    k_sage<true, false><<<NBLK, 512, 0, stream>>>(x, nullptr, off, elist,
                                                  wbl, wbr, b, out, partials);
    k_reduce<<<128, 256, 0, stream>>>(partials, gamma, beta, affine);

    // layer 1: h0(+affine0) -> h1 (in ws), ELU
    k_sage<true, true><<<NBLK, 512, 0, stream>>>(out, affine, off, elist,
                                                 wbl + DD * DD, wbr + DD * DD, b + DD,
                                                 hbuf, partials);
    k_reduce<<<128, 256, 0, stream>>>(partials, gamma + DD, beta + DD, affine);

    // layer 2: h1(+affine1) -> h2 (in d_out), no ELU
    k_sage<false, true><<<NBLK, 512, 0, stream>>>(hbuf, affine, off, elist,
                                                  wbl + 2 * DD * DD, wbr + 2 * DD * DD,
                                                  b + 2 * DD, out, partials);
    k_reduce<<<128, 256, 0, stream>>>(partials, gamma + 2 * DD, beta + 2 * DD, affine);

    // final BN apply in place
    k_apply<<<(N_NODES * DD / 4 + 255) / 256, 256, 0, stream>>>(out, affine);
}

// Round 2
// 532.899 us; speedup vs baseline: 1.6295x; 1.6295x over previous
//
#include <hip/hip_runtime.h>
#include <hip/hip_bf16.h>

#define N_NODES 100000
#define N_EDGES 800000
#define DD 128
#define NBLK 782          // ceil(N_NODES / 128)
#define NSCAN1 391        // ceil(N_NODES / 256)
#define EPSV 1e-5f

typedef short bf16x8 __attribute__((ext_vector_type(8)));
typedef short bf16x4 __attribute__((ext_vector_type(4)));
typedef float f32x4 __attribute__((ext_vector_type(4)));

__device__ __forceinline__ short f2bf(float f) {
    unsigned u = __float_as_uint(f);
    unsigned r = (u + 0x7fffu + ((u >> 16) & 1u)) >> 16;  // RNE
    return (short)r;
}
__device__ __forceinline__ float bf2f(short s) {
    return __uint_as_float(((unsigned)(unsigned short)s) << 16);
}

// ---------------- CSR build ----------------
__global__ void k_count(const int* __restrict__ dst, int* __restrict__ cnt) {
    int e = blockIdx.x * 256 + threadIdx.x;
    if (e < N_EDGES) atomicAdd(&cnt[dst[e]], 1);
}

__global__ void k_scan1(const int* __restrict__ cnt, int* __restrict__ off,
                        int* __restrict__ bsums) {
    __shared__ int s[256];
    int i = blockIdx.x * 256 + threadIdx.x;
    int t = threadIdx.x;
    s[t] = (i < N_NODES) ? cnt[i] : 0;
    __syncthreads();
    for (int d = 1; d < 256; d <<= 1) {
        int x = 0;
        if (t >= d) x = s[t - d];
        __syncthreads();
        s[t] += x;
        __syncthreads();
    }
    if (i < N_NODES) off[i + 1] = s[t];
    if (t == 255) bsums[blockIdx.x] = s[255];
}

__global__ void k_scan2(int* __restrict__ bsums) {
    __shared__ int s[512];
    int t = threadIdx.x;
    s[t] = (t < NSCAN1) ? bsums[t] : 0;
    __syncthreads();
    for (int d = 1; d < 512; d <<= 1) {
        int x = 0;
        if (t >= d) x = s[t - d];
        __syncthreads();
        s[t] += x;
        __syncthreads();
    }
    if (t < NSCAN1) bsums[t] = s[t];   // inclusive
}

__global__ void k_scan3(int* __restrict__ off, const int* __restrict__ bsums) {
    int i = blockIdx.x * 256 + threadIdx.x;
    int add = (blockIdx.x > 0) ? bsums[blockIdx.x - 1] : 0;
    if (i < N_NODES) off[i + 1] += add;
    if (i == 0) off[0] = 0;
}

__global__ void k_fill(const int* __restrict__ src, const int* __restrict__ dst,
                       const int* __restrict__ off, int* __restrict__ cur,
                       int* __restrict__ elist) {
    int e = blockIdx.x * 256 + threadIdx.x;
    if (e < N_EDGES) {
        int d = dst[e];
        int p = atomicAdd(&cur[d], 1);
        elist[off[d] + p] = src[e];
    }
}

// ---------------- x fp32 -> bf16 ----------------
__global__ void k_x2bf(const float* __restrict__ x, short* __restrict__ xbf) {
    int i = blockIdx.x * 256 + threadIdx.x;
    if (i < N_NODES * DD / 4) {
        f32x4 v = *(const f32x4*)(x + (size_t)i * 4);
        bf16x4 t;
        t[0] = f2bf(v.x); t[1] = f2bf(v.y); t[2] = f2bf(v.z); t[3] = f2bf(v.w);
        *(bf16x4*)&xbf[(size_t)i * 4] = t;
    }
}

// ---------------- fold BN affine into weights/bias ----------------
// wbl[o][k] = bf16(Wl[o][k]*a[k]); wbr likewise.
// bias_base[o] = b[o] + sum_k c[k]*Wr[o][k]   (root branch affine offset)
// bias_deg[o]  = sum_k c[k]*Wl[o][k]          (agg branch offset, deg>0 only)
__global__ void k_fold(const float* __restrict__ wl, const float* __restrict__ wr,
                       const float* __restrict__ b, const float* __restrict__ aff,
                       int use_aff,
                       short* __restrict__ wblo, short* __restrict__ wbro,
                       float* __restrict__ bias_base, float* __restrict__ bias_deg) {
    int o = blockIdx.x;     // 0..127
    int k = threadIdx.x;    // 0..127
    float a = use_aff ? aff[k] : 1.f;
    float c = use_aff ? aff[128 + k] : 0.f;
    float vl = wl[o * DD + k], vr = wr[o * DD + k];
    wblo[o * DD + k] = f2bf(vl * a);
    wbro[o * DD + k] = f2bf(vr * a);
    __shared__ float s1[128], s2[128];
    s1[k] = c * vr; s2[k] = c * vl;
    __syncthreads();
    for (int d = 64; d > 0; d >>= 1) {
        if (k < d) { s1[k] += s1[k + d]; s2[k] += s2[k + d]; }
        __syncthreads();
    }
    if (k == 0) {
        bias_base[o] = b[o] + s1[0];
        bias_deg[o] = s2[0];
    }
}

// ---------------- fused SAGE layer ----------------
// block: 512 threads (8 waves), 128 nodes. LDS: one 128x128 bf16 agg tile (32KB).
// Gather: quarter-wave (16 lanes x bf16x8 = full 256B row) per edge -> 4 edges
// in flight per wave, hand-unrolled x2 -> 8 outstanding row loads.
// Root branch read directly from global bf16 (no LDS tile).
template <bool ELU_ON, bool OUT_BF>
__global__ __launch_bounds__(512, 8) void k_sage(
    const short* __restrict__ xbf,
    const int* __restrict__ off, const int* __restrict__ elist,
    const short* __restrict__ wl, const short* __restrict__ wr,
    const float* __restrict__ bias_base, const float* __restrict__ bias_deg,
    short* __restrict__ houtb, float* __restrict__ houtf,
    float* __restrict__ partials)
{
    __shared__ short agg_t[128 * 128];
    __shared__ int sdeg[128];
    const int tid = threadIdx.x;
    const int w = tid >> 6;
    const int l = tid & 63;
    const int base = blockIdx.x * 128;
    const int qw = l >> 4;        // 0..3 quarter-wave
    const int ll = l & 15;        // lane within quarter-wave: cols 8*ll..8*ll+7

    // ---- gather phase: wave w owns rows w*16 .. w*16+15 ----
    for (int i = 0; i < 16; ++i) {
        int m = w * 16 + i;
        int g = base + m;
        float ac0[8], ac1[8];
#pragma unroll
        for (int j = 0; j < 8; ++j) { ac0[j] = 0.f; ac1[j] = 0.f; }
        int deg = 0;
        if (g < N_NODES) {
            int e0 = off[g], e1 = off[g + 1];
            deg = e1 - e0;
            int e = e0 + qw;
            for (; e + 4 < e1; e += 8) {
                int sn0 = elist[e];
                int sn1 = elist[e + 4];
                bf16x8 v0 = *(const bf16x8*)(xbf + (size_t)sn0 * DD + 8 * ll);
                bf16x8 v1 = *(const bf16x8*)(xbf + (size_t)sn1 * DD + 8 * ll);
#pragma unroll
                for (int j = 0; j < 8; ++j) ac0[j] += bf2f(v0[j]);
#pragma unroll
                for (int j = 0; j < 8; ++j) ac1[j] += bf2f(v1[j]);
            }
            if (e < e1) {
                int sn0 = elist[e];
                bf16x8 v0 = *(const bf16x8*)(xbf + (size_t)sn0 * DD + 8 * ll);
#pragma unroll
                for (int j = 0; j < 8; ++j) ac0[j] += bf2f(v0[j]);
            }
        }
#pragma unroll
        for (int j = 0; j < 8; ++j) {
            float s = ac0[j] + ac1[j];
            s += __shfl_xor(s, 16, 64);
            s += __shfl_xor(s, 32, 64);
            ac0[j] = s;
        }
        if (l == 0) sdeg[m] = deg;
        if (qw == 0) {
            float inv = deg > 0 ? 1.f / (float)deg : 0.f;
            bf16x8 t;
#pragma unroll
            for (int j = 0; j < 8; ++j) t[j] = f2bf(ac0[j] * inv);
            *(bf16x8*)&agg_t[m * DD + ((8 * ll) ^ ((m & 7) << 3))] = t;
        }
    }
    __syncthreads();

    // ---- MFMA phase: wave w computes rows w*16..+15 x 128 cols ----
    f32x4 acc[8];
#pragma unroll
    for (int nb = 0; nb < 8; ++nb) acc[nb] = f32x4{0.f, 0.f, 0.f, 0.f};
    const int mrow = w * 16 + (l & 15);
    const int kg = (l >> 4) * 8;
    const int nloc = l & 15;
    const int groot = min(base + mrow, N_NODES - 1);
#pragma unroll
    for (int ks = 0; ks < 4; ++ks) {
        int kk = ks * 32 + kg;
        int sw = kk ^ ((mrow & 7) << 3);
        bf16x8 aa = *(const bf16x8*)&agg_t[mrow * DD + sw];
        bf16x8 ax = *(const bf16x8*)(xbf + (size_t)groot * DD + kk);
#pragma unroll
        for (int nb = 0; nb < 8; ++nb) {
            int n = nb * 16 + nloc;
            bf16x8 bl = *(const bf16x8*)&wl[n * DD + kk];
            bf16x8 br = *(const bf16x8*)&wr[n * DD + kk];
            acc[nb] = __builtin_amdgcn_mfma_f32_16x16x32_bf16(aa, bl, acc[nb], 0, 0, 0);
            acc[nb] = __builtin_amdgcn_mfma_f32_16x16x32_bf16(ax, br, acc[nb], 0, 0, 0);
        }
    }

    // ---- epilogue: bias, ELU, store, column stats ----
    int degf[4];
#pragma unroll
    for (int r = 0; r < 4; ++r) degf[r] = sdeg[w * 16 + (l >> 4) * 4 + r];

    float colS[8], colQ[8];
#pragma unroll
    for (int nb = 0; nb < 8; ++nb) {
        int n = nb * 16 + nloc;
        float bb = bias_base[n];
        float bd = bias_deg[n];
        float cs = 0.f, cq = 0.f;
#pragma unroll
        for (int r = 0; r < 4; ++r) {
            int m = w * 16 + (l >> 4) * 4 + r;
            int g = base + m;
            float hv = acc[nb][r] + bb + (degf[r] > 0 ? bd : 0.f);
            if (ELU_ON) hv = hv > 0.f ? hv : expm1f(hv);
            bool valid = g < N_NODES;
            if (valid) {
                if (OUT_BF) houtb[(size_t)g * DD + n] = f2bf(hv);
                else        houtf[(size_t)g * DD + n] = hv;
            }
            float hm = valid ? hv : 0.f;
            cs += hm;
            cq += hm * hm;
        }
        colS[nb] = cs; colQ[nb] = cq;
    }
#pragma unroll
    for (int nb = 0; nb < 8; ++nb) {
        colS[nb] += __shfl_xor(colS[nb], 16, 64);
        colS[nb] += __shfl_xor(colS[nb], 32, 64);
        colQ[nb] += __shfl_xor(colQ[nb], 16, 64);
        colQ[nb] += __shfl_xor(colQ[nb], 32, 64);
    }
    __syncthreads();                      // all agg_t reads done
    float* sl = (float*)agg_t;            // reuse: 8 waves * 256 floats
    if (l < 16) {
#pragma unroll
        for (int nb = 0; nb < 8; ++nb) {
            sl[w * 256 + nb * 16 + l]       = colS[nb];
            sl[w * 256 + 128 + nb * 16 + l] = colQ[nb];
        }
    }
    __syncthreads();
    if (tid < 256) {
        float t = 0.f;
#pragma unroll
        for (int w2 = 0; w2 < 8; ++w2) t += sl[w2 * 256 + tid];
        partials[blockIdx.x * 256 + tid] = t;
    }
}

// ---------------- BN stats -> affine ----------------
__global__ void k_reduce(const float* __restrict__ partials,
                         const float* __restrict__ gamma, const float* __restrict__ beta,
                         float* __restrict__ aff) {
    int f = blockIdx.x;     // 0..127
    int t = threadIdx.x;    // 256
    float s = 0.f, q = 0.f;
    for (int i = t; i < NBLK; i += 256) {
        s += partials[i * 256 + f];
        q += partials[i * 256 + 128 + f];
    }
    __shared__ float rs[256], rq[256];
    rs[t] = s; rq[t] = q;
    __syncthreads();
    for (int d = 128; d > 0; d >>= 1) {
        if (t < d) { rs[t] += rs[t + d]; rq[t] += rq[t + d]; }
        __syncthreads();
    }
    if (t == 0) {
        float mean = rs[0] / (float)N_NODES;
        float var = rq[0] / (float)N_NODES - mean * mean;
        float a = gamma[f] * rsqrtf(var + EPSV);
        aff[f] = a;
        aff[128 + f] = beta[f] - mean * a;
    }
}

// ---------------- final BN apply (in place) ----------------
__global__ void k_apply(float* __restrict__ out, const float* __restrict__ aff) {
    int i = blockIdx.x * 256 + threadIdx.x;  // float4 index
    if (i < N_NODES * DD / 4) {
        f32x4 v = *(f32x4*)(out + (size_t)i * 4);
        int f = (i * 4) & 127;
        f32x4 a = *(const f32x4*)(aff + f);
        f32x4 c = *(const f32x4*)(aff + 128 + f);
        v = a * v + c;
        *(f32x4*)(out + (size_t)i * 4) = v;
    }
}

extern "C" void kernel_launch(void* const* d_in, const int* in_sizes, int n_in,
                              void* d_out, int out_size, void* d_ws, size_t ws_size,
                              hipStream_t stream) {
    const float* x     = (const float*)d_in[0];
    const int*   ei    = (const int*)d_in[1];
    const float* Wl    = (const float*)d_in[2];
    const float* Wr    = (const float*)d_in[3];
    const float* b     = (const float*)d_in[4];
    const float* gamma = (const float*)d_in[5];
    const float* beta  = (const float*)d_in[6];
    float* out = (float*)d_out;

    char* ws = (char*)d_ws;
    int*   off      = (int*)(ws + 0);              // (N+1) ints
    int*   cnt      = (int*)(ws + 400128);         // N ints (also cursor)
    int*   elist    = (int*)(ws + 800256);         // E ints
    int*   bsums    = (int*)(ws + 4000256);        // 512 ints
    float* partials = (float*)(ws + 4002304);      // NBLK*256 floats
    float* affine   = (float*)(ws + 4803328);      // 256 floats
    short* wbl      = (short*)(ws + 4804352);      // 128*128 bf16 folded
    short* wbr      = (short*)(ws + 4837120);      // 128*128 bf16 folded
    float* biasb    = (float*)(ws + 4869888);      // 128 floats
    float* biasd    = (float*)(ws + 4870400);      // 128 floats
    short* bufA     = (short*)(ws + 4871168);      // N*D bf16: xbf, then h1
    short* bufB     = (short*)(ws + 30471168);     // N*D bf16: h0

    const int* src = ei;
    const int* dst = ei + N_EDGES;

    // CSR build
    hipMemsetAsync(cnt, 0, N_NODES * sizeof(int), stream);
    k_count<<<(N_EDGES + 255) / 256, 256, 0, stream>>>(dst, cnt);
    k_scan1<<<NSCAN1, 256, 0, stream>>>(cnt, off, bsums);
    k_scan2<<<1, 512, 0, stream>>>(bsums);
    k_scan3<<<NSCAN1, 256, 0, stream>>>(off, bsums);
    hipMemsetAsync(cnt, 0, N_NODES * sizeof(int), stream);
    k_fill<<<(N_EDGES + 255) / 256, 256, 0, stream>>>(src, dst, off, cnt, elist);

    // x -> bf16
    k_x2bf<<<(N_NODES * DD / 4 + 255) / 256, 256, 0, stream>>>(x, bufA);

    // layer 0: xbf(bufA) -> h0 bf16 (bufB), ELU, identity affine
    k_fold<<<128, 128, 0, stream>>>(Wl, Wr, b, affine, 0, wbl, wbr, biasb, biasd);
    k_sage<true, true><<<NBLK, 512, 0, stream>>>(bufA, off, elist, wbl, wbr,
                                                 biasb, biasd, bufB, nullptr, partials);
    k_reduce<<<128, 256, 0, stream>>>(partials, gamma, beta, affine);

    // layer 1: h0(bufB) -> h1 bf16 (bufA), ELU, affine folded
    k_fold<<<128, 128, 0, stream>>>(Wl + DD * DD, Wr + DD * DD, b + DD, affine, 1,
                                    wbl, wbr, biasb, biasd);
    k_sage<true, true><<<NBLK, 512, 0, stream>>>(bufB, off, elist, wbl, wbr,
                                                 biasb, biasd, bufA, nullptr, partials);
    k_reduce<<<128, 256, 0, stream>>>(partials, gamma + DD, beta + DD, affine);

    // layer 2: h1(bufA) -> h2 fp32 (d_out), no ELU, affine folded
    k_fold<<<128, 128, 0, stream>>>(Wl + 2 * DD * DD, Wr + 2 * DD * DD, b + 2 * DD,
                                    affine, 1, wbl, wbr, biasb, biasd);
    k_sage<false, false><<<NBLK, 512, 0, stream>>>(bufA, off, elist, wbl, wbr,
                                                   biasb, biasd, nullptr, out, partials);
    k_reduce<<<128, 256, 0, stream>>>(partials, gamma + 2 * DD, beta + 2 * DD, affine);

    // final BN apply in place
    k_apply<<<(N_NODES * DD / 4 + 255) / 256, 256, 0, stream>>>(out, affine);
}

// Round 3
// 430.877 us; speedup vs baseline: 2.0153x; 1.2368x over previous
//
#include <hip/hip_runtime.h>
#include <hip/hip_bf16.h>

#define N_NODES 100000
#define N_EDGES 800000
#define DD 128
#define NBLK 1563         // ceil(N_NODES / 64)
#define NSCAN1 391        // ceil(N_NODES / 256)
#define EPSV 1e-5f

typedef short bf16x8 __attribute__((ext_vector_type(8)));
typedef short bf16x4 __attribute__((ext_vector_type(4)));
typedef float f32x4 __attribute__((ext_vector_type(4)));

__device__ __forceinline__ short f2bf(float f) {
    unsigned u = __float_as_uint(f);
    unsigned r = (u + 0x7fffu + ((u >> 16) & 1u)) >> 16;  // RNE
    return (short)r;
}
__device__ __forceinline__ float bf2f(short s) {
    return __uint_as_float(((unsigned)(unsigned short)s) << 16);
}

// ---------------- setup: x fp32->bf16 fused with degree count ----------------
__global__ void k_setup(const float* __restrict__ x, short* __restrict__ xbf,
                        const int* __restrict__ dst, int* __restrict__ cnt) {
    int i = blockIdx.x * 256 + threadIdx.x;
    if (i < N_NODES * DD / 8) {
        f32x4 v0 = *(const f32x4*)(x + (size_t)i * 8);
        f32x4 v1 = *(const f32x4*)(x + (size_t)i * 8 + 4);
        bf16x8 t;
        t[0] = f2bf(v0.x); t[1] = f2bf(v0.y); t[2] = f2bf(v0.z); t[3] = f2bf(v0.w);
        t[4] = f2bf(v1.x); t[5] = f2bf(v1.y); t[6] = f2bf(v1.z); t[7] = f2bf(v1.w);
        *(bf16x8*)&xbf[(size_t)i * 8] = t;
    }
    if (i < N_EDGES) atomicAdd(&cnt[dst[i]], 1);
}

// ---------------- CSR build ----------------
__global__ void k_scan1(const int* __restrict__ cnt, int* __restrict__ off,
                        int* __restrict__ bsums) {
    __shared__ int s[256];
    int i = blockIdx.x * 256 + threadIdx.x;
    int t = threadIdx.x;
    s[t] = (i < N_NODES) ? cnt[i] : 0;
    __syncthreads();
    for (int d = 1; d < 256; d <<= 1) {
        int x = 0;
        if (t >= d) x = s[t - d];
        __syncthreads();
        s[t] += x;
        __syncthreads();
    }
    if (i < N_NODES) off[i + 1] = s[t];
    if (t == 255) bsums[blockIdx.x] = s[255];
}

__global__ void k_scan2(int* __restrict__ bsums) {
    __shared__ int s[512];
    int t = threadIdx.x;
    s[t] = (t < NSCAN1) ? bsums[t] : 0;
    __syncthreads();
    for (int d = 1; d < 512; d <<= 1) {
        int x = 0;
        if (t >= d) x = s[t - d];
        __syncthreads();
        s[t] += x;
        __syncthreads();
    }
    if (t < NSCAN1) bsums[t] = s[t];   // inclusive
}

__global__ void k_scan3(int* __restrict__ off, const int* __restrict__ bsums) {
    int i = blockIdx.x * 256 + threadIdx.x;
    int add = (blockIdx.x > 0) ? bsums[blockIdx.x - 1] : 0;
    if (i < N_NODES) off[i + 1] += add;
    if (i == 0) off[0] = 0;
}

// uses cnt (still holding counts) as a down-counter: no second memset needed
__global__ void k_fill(const int* __restrict__ src, const int* __restrict__ dst,
                       const int* __restrict__ off, int* __restrict__ cur,
                       int* __restrict__ elist) {
    int e = blockIdx.x * 256 + threadIdx.x;
    if (e < N_EDGES) {
        int d = dst[e];
        int p = atomicSub(&cur[d], 1);   // old value >= 1
        elist[off[d] + p - 1] = src[e];
    }
}

// ---------------- fold BN affine into weights/bias ----------------
__global__ void k_fold(const float* __restrict__ wl, const float* __restrict__ wr,
                       const float* __restrict__ b, const float* __restrict__ aff,
                       int use_aff,
                       short* __restrict__ wblo, short* __restrict__ wbro,
                       float* __restrict__ bias_base, float* __restrict__ bias_deg) {
    int o = blockIdx.x;     // 0..127
    int k = threadIdx.x;    // 0..127
    float a = use_aff ? aff[k] : 1.f;
    float c = use_aff ? aff[128 + k] : 0.f;
    float vl = wl[o * DD + k], vr = wr[o * DD + k];
    wblo[o * DD + k] = f2bf(vl * a);
    wbro[o * DD + k] = f2bf(vr * a);
    __shared__ float s1[128], s2[128];
    s1[k] = c * vr; s2[k] = c * vl;
    __syncthreads();
    for (int d = 64; d > 0; d >>= 1) {
        if (k < d) { s1[k] += s1[k + d]; s2[k] += s2[k + d]; }
        __syncthreads();
    }
    if (k == 0) {
        bias_base[o] = b[o] + s1[0];
        bias_deg[o] = s2[0];
    }
}

// ---------------- fused SAGE layer ----------------
// 64-node tile, 512 threads (8 waves). Wave pair p=(w>>1) shares a 16-row MFMA
// tile; wave w gathers 8 rows ((w&1)*8..+7 of the pair) and computes the
// (w&1) 64-col half of the pair's output. Gather: quarter-wave = full 256B row,
// row-pair interleave + 2-deep unroll = 16 outstanding row loads per wave.
template <bool ELU_ON>
__global__ __launch_bounds__(512, 6) void k_sage(
    const short* __restrict__ xbf,
    const int* __restrict__ off, const int* __restrict__ elist,
    const short* __restrict__ wl, const short* __restrict__ wr,
    const float* __restrict__ bias_base, const float* __restrict__ bias_deg,
    short* __restrict__ hout, float* __restrict__ partials)
{
    __shared__ short agg_t[64 * 128];    // 16KB: agg tile, then reused as C tile
    __shared__ int sdeg[64];
    __shared__ float sstat[8 * 128];     // per-wave column stats staging
    const int tid = threadIdx.x;
    const int wu = __builtin_amdgcn_readfirstlane(tid >> 6);
    const int l = tid & 63;
    const int base = blockIdx.x * 64;
    const int qw = l >> 4;        // quarter-wave 0..3
    const int ll = l & 15;        // lane in quarter-wave: cols 8*ll..8*ll+7

    // ---- gather phase: wave wu owns rows growb..growb+7 ----
    const int growb = (wu >> 1) * 16 + (wu & 1) * 8;
    for (int i = 0; i < 8; i += 2) {
        const int m0 = growb + i;
        const int m1 = m0 + 1;
        const int g0 = base + m0;
        const int g1 = base + m1;
        float A0[8], A1[8], B0[8], B1[8];
#pragma unroll
        for (int j = 0; j < 8; ++j) { A0[j] = A1[j] = B0[j] = B1[j] = 0.f; }
        int ea = 0, eA = 0, eb = 0, eB = 0;
        if (g0 < N_NODES) { ea = off[g0]; eA = off[g0 + 1]; }
        if (g1 < N_NODES) { eb = off[g1]; eB = off[g1 + 1]; }
        const int dA = eA - ea, dB = eB - eb;
        int e = ea + qw;
        int f = eb + qw;
        // both rows active: 4 row-loads in flight per quarter-wave
        while (e + 4 < eA && f + 4 < eB) {
            int s0 = elist[e], s1 = elist[e + 4];
            int s2 = elist[f], s3 = elist[f + 4];
            bf16x8 v0 = *(const bf16x8*)(xbf + (size_t)s0 * DD + 8 * ll);
            bf16x8 v1 = *(const bf16x8*)(xbf + (size_t)s1 * DD + 8 * ll);
            bf16x8 v2 = *(const bf16x8*)(xbf + (size_t)s2 * DD + 8 * ll);
            bf16x8 v3 = *(const bf16x8*)(xbf + (size_t)s3 * DD + 8 * ll);
#pragma unroll
            for (int j = 0; j < 8; ++j) {
                A0[j] += bf2f(v0[j]); A1[j] += bf2f(v1[j]);
                B0[j] += bf2f(v2[j]); B1[j] += bf2f(v3[j]);
            }
            e += 8; f += 8;
        }
        while (e + 4 < eA) {
            int s0 = elist[e], s1 = elist[e + 4];
            bf16x8 v0 = *(const bf16x8*)(xbf + (size_t)s0 * DD + 8 * ll);
            bf16x8 v1 = *(const bf16x8*)(xbf + (size_t)s1 * DD + 8 * ll);
#pragma unroll
            for (int j = 0; j < 8; ++j) { A0[j] += bf2f(v0[j]); A1[j] += bf2f(v1[j]); }
            e += 8;
        }
        if (e < eA) {
            int s0 = elist[e];
            bf16x8 v0 = *(const bf16x8*)(xbf + (size_t)s0 * DD + 8 * ll);
#pragma unroll
            for (int j = 0; j < 8; ++j) A0[j] += bf2f(v0[j]);
        }
        while (f + 4 < eB) {
            int s2 = elist[f], s3 = elist[f + 4];
            bf16x8 v2 = *(const bf16x8*)(xbf + (size_t)s2 * DD + 8 * ll);
            bf16x8 v3 = *(const bf16x8*)(xbf + (size_t)s3 * DD + 8 * ll);
#pragma unroll
            for (int j = 0; j < 8; ++j) { B0[j] += bf2f(v2[j]); B1[j] += bf2f(v3[j]); }
            f += 8;
        }
        if (f < eB) {
            int s2 = elist[f];
            bf16x8 v2 = *(const bf16x8*)(xbf + (size_t)s2 * DD + 8 * ll);
#pragma unroll
            for (int j = 0; j < 8; ++j) B0[j] += bf2f(v2[j]);
        }
#pragma unroll
        for (int j = 0; j < 8; ++j) {
            float sA = A0[j] + A1[j];
            sA += __shfl_xor(sA, 16, 64);
            sA += __shfl_xor(sA, 32, 64);
            A0[j] = sA;
            float sB = B0[j] + B1[j];
            sB += __shfl_xor(sB, 16, 64);
            sB += __shfl_xor(sB, 32, 64);
            B0[j] = sB;
        }
        if (l == 0) { sdeg[m0] = dA; sdeg[m1] = dB; }
        if (qw == 0) {
            float invA = dA > 0 ? 1.f / (float)dA : 0.f;
            float invB = dB > 0 ? 1.f / (float)dB : 0.f;
            bf16x8 tA, tB;
#pragma unroll
            for (int j = 0; j < 8; ++j) { tA[j] = f2bf(A0[j] * invA); tB[j] = f2bf(B0[j] * invB); }
            *(bf16x8*)&agg_t[m0 * DD + ((8 * ll) ^ ((m0 & 7) << 3))] = tA;
            *(bf16x8*)&agg_t[m1 * DD + ((8 * ll) ^ ((m1 & 7) << 3))] = tB;
        }
    }
    __syncthreads();

    // ---- MFMA phase: wave = 16 rows (pair) x 64 cols (half) ----
    const int p = wu >> 1;
    const int half = wu & 1;
    f32x4 acc[4];
#pragma unroll
    for (int nb = 0; nb < 4; ++nb) acc[nb] = f32x4{0.f, 0.f, 0.f, 0.f};
    const int mrow = p * 16 + (l & 15);
    const int kg = (l >> 4) * 8;
    const int nloc = l & 15;
    const int groot = min(base + mrow, N_NODES - 1);
#pragma unroll
    for (int ks = 0; ks < 4; ++ks) {
        int kk = ks * 32 + kg;
        int sw = kk ^ ((mrow & 7) << 3);
        bf16x8 aa = *(const bf16x8*)&agg_t[mrow * DD + sw];
        bf16x8 ax = *(const bf16x8*)(xbf + (size_t)groot * DD + kk);
#pragma unroll
        for (int nb = 0; nb < 4; ++nb) {
            int n = half * 64 + nb * 16 + nloc;
            bf16x8 bl = *(const bf16x8*)&wl[n * DD + kk];
            bf16x8 br = *(const bf16x8*)&wr[n * DD + kk];
            acc[nb] = __builtin_amdgcn_mfma_f32_16x16x32_bf16(aa, bl, acc[nb], 0, 0, 0);
            acc[nb] = __builtin_amdgcn_mfma_f32_16x16x32_bf16(ax, br, acc[nb], 0, 0, 0);
        }
    }
    __syncthreads();   // agg tile reads done by both waves of every pair

    // ---- epilogue: bias, ELU, stats, C tile into LDS ----
    int degf[4];
#pragma unroll
    for (int r = 0; r < 4; ++r) degf[r] = sdeg[p * 16 + (l >> 4) * 4 + r];

    float colS[4], colQ[4];
#pragma unroll
    for (int nb = 0; nb < 4; ++nb) {
        int n = half * 64 + nb * 16 + nloc;
        float bb = bias_base[n];
        float bd = bias_deg[n];
        float cs = 0.f, cq = 0.f;
#pragma unroll
        for (int r = 0; r < 4; ++r) {
            int m = p * 16 + (l >> 4) * 4 + r;
            int g = base + m;
            float hv = acc[nb][r] + bb + (degf[r] > 0 ? bd : 0.f);
            if (ELU_ON) hv = hv > 0.f ? hv : expm1f(hv);
            agg_t[m * DD + (n ^ ((m & 7) << 3))] = f2bf(hv);
            float hm = (g < N_NODES) ? hv : 0.f;
            cs += hm;
            cq += hm * hm;
        }
        colS[nb] = cs; colQ[nb] = cq;
    }
#pragma unroll
    for (int nb = 0; nb < 4; ++nb) {
        colS[nb] += __shfl_xor(colS[nb], 16, 64);
        colS[nb] += __shfl_xor(colS[nb], 32, 64);
        colQ[nb] += __shfl_xor(colQ[nb], 16, 64);
        colQ[nb] += __shfl_xor(colQ[nb], 32, 64);
    }
    if (l < 16) {
#pragma unroll
        for (int nb = 0; nb < 4; ++nb) {
            sstat[wu * 128 + nb * 16 + l]      = colS[nb];
            sstat[wu * 128 + 64 + nb * 16 + l] = colQ[nb];
        }
    }
    __syncthreads();

    // ---- coalesced C write-out + stats combine ----
#pragma unroll
    for (int k = 0; k < 2; ++k) {
        int idx = (k * 512 + tid) * 8;           // short index in 64x128 tile
        int m = idx >> 7, c = idx & 127;
        int g = base + m;
        if (g < N_NODES) {
            bf16x8 v = *(const bf16x8*)&agg_t[m * DD + (c ^ ((m & 7) << 3))];
            *(bf16x8*)&hout[(size_t)g * DD + c] = v;
        }
    }
    if (tid < 256) {
        int f = tid & 127;
        int part = tid >> 7;                     // 0 = sum, 1 = sumsq
        int hsel = f >> 6;                       // which col-half wave
        int cw = part * 64 + (f & 63);
        float v = 0.f;
#pragma unroll
        for (int pr = 0; pr < 4; ++pr) v += sstat[(2 * pr + hsel) * 128 + cw];
        partials[blockIdx.x * 256 + tid] = v;
    }
}

// ---------------- BN stats -> affine ----------------
__global__ void k_reduce(const float* __restrict__ partials,
                         const float* __restrict__ gamma, const float* __restrict__ beta,
                         float* __restrict__ aff) {
    int f = blockIdx.x;     // 0..127
    int t = threadIdx.x;    // 256
    float s = 0.f, q = 0.f;
    for (int i = t; i < NBLK; i += 256) {
        s += partials[i * 256 + f];
        q += partials[i * 256 + 128 + f];
    }
    __shared__ float rs[256], rq[256];
    rs[t] = s; rq[t] = q;
    __syncthreads();
    for (int d = 128; d > 0; d >>= 1) {
        if (t < d) { rs[t] += rs[t + d]; rq[t] += rq[t + d]; }
        __syncthreads();
    }
    if (t == 0) {
        float mean = rs[0] / (float)N_NODES;
        float var = rq[0] / (float)N_NODES - mean * mean;
        float a = gamma[f] * rsqrtf(var + EPSV);
        aff[f] = a;
        aff[128 + f] = beta[f] - mean * a;
    }
}

// ---------------- final BN apply: bf16 h2 -> fp32 out ----------------
__global__ void k_apply(const short* __restrict__ hin, const float* __restrict__ aff,
                        float* __restrict__ out) {
    int i = blockIdx.x * 256 + threadIdx.x;  // bf16x8 units
    if (i < N_NODES * DD / 8) {
        bf16x8 v = *(const bf16x8*)(hin + (size_t)i * 8);
        int f = (i * 8) & 127;
        f32x4 a0 = *(const f32x4*)(aff + f);
        f32x4 a1 = *(const f32x4*)(aff + f + 4);
        f32x4 c0 = *(const f32x4*)(aff + 128 + f);
        f32x4 c1 = *(const f32x4*)(aff + 128 + f + 4);
        f32x4 o0, o1;
        o0.x = bf2f(v[0]) * a0.x + c0.x; o0.y = bf2f(v[1]) * a0.y + c0.y;
        o0.z = bf2f(v[2]) * a0.z + c0.z; o0.w = bf2f(v[3]) * a0.w + c0.w;
        o1.x = bf2f(v[4]) * a1.x + c1.x; o1.y = bf2f(v[5]) * a1.y + c1.y;
        o1.z = bf2f(v[6]) * a1.z + c1.z; o1.w = bf2f(v[7]) * a1.w + c1.w;
        *(f32x4*)(out + (size_t)i * 8) = o0;
        *(f32x4*)(out + (size_t)i * 8 + 4) = o1;
    }
}

extern "C" void kernel_launch(void* const* d_in, const int* in_sizes, int n_in,
                              void* d_out, int out_size, void* d_ws, size_t ws_size,
                              hipStream_t stream) {
    const float* x     = (const float*)d_in[0];
    const int*   ei    = (const int*)d_in[1];
    const float* Wl    = (const float*)d_in[2];
    const float* Wr    = (const float*)d_in[3];
    const float* b     = (const float*)d_in[4];
    const float* gamma = (const float*)d_in[5];
    const float* beta  = (const float*)d_in[6];
    float* out = (float*)d_out;

    char* ws = (char*)d_ws;
    int*   off      = (int*)(ws + 0);              // (N+1) ints
    int*   cnt      = (int*)(ws + 400128);         // N ints (count, then cursor)
    int*   elist    = (int*)(ws + 800256);         // E ints
    int*   bsums    = (int*)(ws + 4000256);        // 512 ints
    float* partials = (float*)(ws + 4002304);      // NBLK*256 floats (1.6MB)
    float* affine   = (float*)(ws + 5603840);      // 256 floats
    short* wbl      = (short*)(ws + 5604864);      // 128*128 bf16 folded
    short* wbr      = (short*)(ws + 5637632);      // 128*128 bf16 folded
    float* biasb    = (float*)(ws + 5670400);      // 128 floats
    float* biasd    = (float*)(ws + 5670912);      // 128 floats
    short* bufA     = (short*)(ws + 5671424);      // N*D bf16: xbf, then h1
    short* bufB     = (short*)(ws + 31271424);     // N*D bf16: h0, then h2

    const int* src = ei;
    const int* dst = ei + N_EDGES;

    // CSR build + x->bf16
    hipMemsetAsync(cnt, 0, N_NODES * sizeof(int), stream);
    k_setup<<<(N_NODES * DD / 8 + 255) / 256, 256, 0, stream>>>(x, bufA, dst, cnt);
    k_scan1<<<NSCAN1, 256, 0, stream>>>(cnt, off, bsums);
    k_scan2<<<1, 512, 0, stream>>>(bsums);
    k_scan3<<<NSCAN1, 256, 0, stream>>>(off, bsums);
    k_fill<<<(N_EDGES + 255) / 256, 256, 0, stream>>>(src, dst, off, cnt, elist);

    // layer 0: xbf(bufA) -> h0 (bufB), ELU, identity affine
    k_fold<<<128, 128, 0, stream>>>(Wl, Wr, b, affine, 0, wbl, wbr, biasb, biasd);
    k_sage<true><<<NBLK, 512, 0, stream>>>(bufA, off, elist, wbl, wbr,
                                           biasb, biasd, bufB, partials);
    k_reduce<<<128, 256, 0, stream>>>(partials, gamma, beta, affine);

    // layer 1: h0(bufB) -> h1 (bufA), ELU, affine folded
    k_fold<<<128, 128, 0, stream>>>(Wl + DD * DD, Wr + DD * DD, b + DD, affine, 1,
                                    wbl, wbr, biasb, biasd);
    k_sage<true><<<NBLK, 512, 0, stream>>>(bufB, off, elist, wbl, wbr,
                                           biasb, biasd, bufA, partials);
    k_reduce<<<128, 256, 0, stream>>>(partials, gamma + DD, beta + DD, affine);

    // layer 2: h1(bufA) -> h2 (bufB), no ELU, affine folded
    k_fold<<<128, 128, 0, stream>>>(Wl + 2 * DD * DD, Wr + 2 * DD * DD, b + 2 * DD,
                                    affine, 1, wbl, wbr, biasb, biasd);
    k_sage<false><<<NBLK, 512, 0, stream>>>(bufA, off, elist, wbl, wbr,
                                            biasb, biasd, bufB, partials);
    k_reduce<<<128, 256, 0, stream>>>(partials, gamma + 2 * DD, beta + 2 * DD, affine);

    // final BN apply: bf16 h2 -> fp32 out
    k_apply<<<(N_NODES * DD / 8 + 255) / 256, 256, 0, stream>>>(bufB, affine, out);
}

// Round 4
// 418.517 us; speedup vs baseline: 2.0748x; 1.0295x over previous
//
#include <hip/hip_runtime.h>
#include <hip/hip_bf16.h>

#define N_NODES 100000
#define N_EDGES 800000
#define DD 128
#define NBLK 1563         // ceil(N_NODES / 64)
#define NSCAN1 391        // ceil(N_NODES / 256)
#define EPSV 1e-5f
#define ECAP 1536         // staged edge-index capacity per 64-node tile (mean 512)

typedef short bf16x8 __attribute__((ext_vector_type(8)));
typedef short bf16x4 __attribute__((ext_vector_type(4)));
typedef float f32x4 __attribute__((ext_vector_type(4)));

__device__ __forceinline__ short f2bf(float f) {
    unsigned u = __float_as_uint(f);
    unsigned r = (u + 0x7fffu + ((u >> 16) & 1u)) >> 16;  // RNE
    return (short)r;
}
__device__ __forceinline__ float bf2f(short s) {
    return __uint_as_float(((unsigned)(unsigned short)s) << 16);
}

// ---------------- setup: x fp32->bf16 fused with degree count ----------------
__global__ void k_setup(const float* __restrict__ x, short* __restrict__ xbf,
                        const int* __restrict__ dst, int* __restrict__ cnt) {
    int i = blockIdx.x * 256 + threadIdx.x;
    if (i < N_NODES * DD / 8) {
        f32x4 v0 = *(const f32x4*)(x + (size_t)i * 8);
        f32x4 v1 = *(const f32x4*)(x + (size_t)i * 8 + 4);
        bf16x8 t;
        t[0] = f2bf(v0.x); t[1] = f2bf(v0.y); t[2] = f2bf(v0.z); t[3] = f2bf(v0.w);
        t[4] = f2bf(v1.x); t[5] = f2bf(v1.y); t[6] = f2bf(v1.z); t[7] = f2bf(v1.w);
        *(bf16x8*)&xbf[(size_t)i * 8] = t;
    }
    if (i < N_EDGES) atomicAdd(&cnt[dst[i]], 1);
}

// ---------------- CSR build ----------------
__global__ void k_scan1(const int* __restrict__ cnt, int* __restrict__ off,
                        int* __restrict__ bsums) {
    __shared__ int s[256];
    int i = blockIdx.x * 256 + threadIdx.x;
    int t = threadIdx.x;
    s[t] = (i < N_NODES) ? cnt[i] : 0;
    __syncthreads();
    for (int d = 1; d < 256; d <<= 1) {
        int x = 0;
        if (t >= d) x = s[t - d];
        __syncthreads();
        s[t] += x;
        __syncthreads();
    }
    if (i < N_NODES) off[i + 1] = s[t];
    if (t == 255) bsums[blockIdx.x] = s[255];
}

__global__ void k_scan2(int* __restrict__ bsums) {
    __shared__ int s[512];
    int t = threadIdx.x;
    s[t] = (t < NSCAN1) ? bsums[t] : 0;
    __syncthreads();
    for (int d = 1; d < 512; d <<= 1) {
        int x = 0;
        if (t >= d) x = s[t - d];
        __syncthreads();
        s[t] += x;
        __syncthreads();
    }
    if (t < NSCAN1) bsums[t] = s[t];   // inclusive
}

__global__ void k_scan3(int* __restrict__ off, const int* __restrict__ bsums) {
    int i = blockIdx.x * 256 + threadIdx.x;
    int add = (blockIdx.x > 0) ? bsums[blockIdx.x - 1] : 0;
    if (i < N_NODES) off[i + 1] += add;
    if (i == 0) off[0] = 0;
}

// uses cnt (still holding counts) as a down-counter: no second memset needed
__global__ void k_fill(const int* __restrict__ src, const int* __restrict__ dst,
                       const int* __restrict__ off, int* __restrict__ cur,
                       int* __restrict__ elist) {
    int e = blockIdx.x * 256 + threadIdx.x;
    if (e < N_EDGES) {
        int d = dst[e];
        int p = atomicSub(&cur[d], 1);   // old value >= 1
        elist[off[d] + p - 1] = src[e];
    }
}

// ---------------- fold BN affine into weights/bias ----------------
__global__ void k_fold(const float* __restrict__ wl, const float* __restrict__ wr,
                       const float* __restrict__ b, const float* __restrict__ aff,
                       int use_aff,
                       short* __restrict__ wblo, short* __restrict__ wbro,
                       float* __restrict__ bias_base, float* __restrict__ bias_deg) {
    int o = blockIdx.x;     // 0..127
    int k = threadIdx.x;    // 0..127
    float a = use_aff ? aff[k] : 1.f;
    float c = use_aff ? aff[128 + k] : 0.f;
    float vl = wl[o * DD + k], vr = wr[o * DD + k];
    wblo[o * DD + k] = f2bf(vl * a);
    wbro[o * DD + k] = f2bf(vr * a);
    __shared__ float s1[128], s2[128];
    s1[k] = c * vr; s2[k] = c * vl;
    __syncthreads();
    for (int d = 64; d > 0; d >>= 1) {
        if (k < d) { s1[k] += s1[k + d]; s2[k] += s2[k + d]; }
        __syncthreads();
    }
    if (k == 0) {
        bias_base[o] = b[o] + s1[0];
        bias_deg[o] = s2[0];
    }
}

// ---------------- fused SAGE layer ----------------
// 64-node tile, 512 threads (8 waves).
// Gather: dynamic row-pair queue (LDS atomic); indices pre-staged in LDS;
// quarter-wave = full 256B row; 2 rows x 2-deep = 16 outstanding rows/wave.
// MFMA: wave pair shares a 16-row tile, each wave one 64-col half.
template <bool ELU_ON>
__global__ __launch_bounds__(512, 6) void k_sage(
    const short* __restrict__ xbf,
    const int* __restrict__ off, const int* __restrict__ elist,
    const short* __restrict__ wl, const short* __restrict__ wr,
    const float* __restrict__ bias_base, const float* __restrict__ bias_deg,
    short* __restrict__ hout, float* __restrict__ partials)
{
    __shared__ short agg_t[64 * 128];    // 16KB: agg tile, then reused as C tile
    __shared__ int sdeg[64];
    __shared__ float sstat[8 * 128];     // per-wave column stats staging
    __shared__ int soff[65];
    __shared__ int eidx[ECAP];
    __shared__ int rowctr;
    const int tid = threadIdx.x;
    const int wu = __builtin_amdgcn_readfirstlane(tid >> 6);
    const int l = tid & 63;
    const int base = blockIdx.x * 64;
    const int qw = l >> 4;        // quarter-wave 0..3
    const int ll = l & 15;        // lane in quarter-wave: cols 8*ll..8*ll+7

    // ---- stage offsets + edge indices into LDS ----
    if (tid < 65) soff[tid] = off[min(base + tid, N_NODES)];
    if (tid == 0) rowctr = 0;
    __syncthreads();
    const int ebase = soff[0];
    const int etot = soff[64] - ebase;
    const bool ovf = etot > ECAP;
    for (int k = tid; k < (ovf ? 0 : etot); k += 512) eidx[k] = elist[ebase + k];
    __syncthreads();
    const int* ep = ovf ? (elist + ebase) : (const int*)eidx;

    // ---- gather phase: dynamic row-pair queue ----
    for (;;) {
        int rp;
        if (l == 0) rp = atomicAdd(&rowctr, 1);
        rp = __shfl(rp, 0, 64);
        if (rp >= 32) break;
        const int m0 = rp * 2;
        const int m1 = m0 + 1;
        const int ea = soff[m0] - ebase, eA = soff[m0 + 1] - ebase;
        const int eb = soff[m1] - ebase, eB = soff[m1 + 1] - ebase;
        const int dA = eA - ea, dB = eB - eb;
        float A0[8], A1[8], B0[8], B1[8];
#pragma unroll
        for (int j = 0; j < 8; ++j) { A0[j] = A1[j] = B0[j] = B1[j] = 0.f; }
        int e = ea + qw;
        int f = eb + qw;
        while (e + 4 < eA && f + 4 < eB) {
            int s0 = ep[e], s1 = ep[e + 4];
            int s2 = ep[f], s3 = ep[f + 4];
            bf16x8 v0 = *(const bf16x8*)(xbf + (size_t)s0 * DD + 8 * ll);
            bf16x8 v1 = *(const bf16x8*)(xbf + (size_t)s1 * DD + 8 * ll);
            bf16x8 v2 = *(const bf16x8*)(xbf + (size_t)s2 * DD + 8 * ll);
            bf16x8 v3 = *(const bf16x8*)(xbf + (size_t)s3 * DD + 8 * ll);
#pragma unroll
            for (int j = 0; j < 8; ++j) {
                A0[j] += bf2f(v0[j]); A1[j] += bf2f(v1[j]);
                B0[j] += bf2f(v2[j]); B1[j] += bf2f(v3[j]);
            }
            e += 8; f += 8;
        }
        while (e + 4 < eA) {
            int s0 = ep[e], s1 = ep[e + 4];
            bf16x8 v0 = *(const bf16x8*)(xbf + (size_t)s0 * DD + 8 * ll);
            bf16x8 v1 = *(const bf16x8*)(xbf + (size_t)s1 * DD + 8 * ll);
#pragma unroll
            for (int j = 0; j < 8; ++j) { A0[j] += bf2f(v0[j]); A1[j] += bf2f(v1[j]); }
            e += 8;
        }
        if (e < eA) {
            int s0 = ep[e];
            bf16x8 v0 = *(const bf16x8*)(xbf + (size_t)s0 * DD + 8 * ll);
#pragma unroll
            for (int j = 0; j < 8; ++j) A0[j] += bf2f(v0[j]);
        }
        while (f + 4 < eB) {
            int s2 = ep[f], s3 = ep[f + 4];
            bf16x8 v2 = *(const bf16x8*)(xbf + (size_t)s2 * DD + 8 * ll);
            bf16x8 v3 = *(const bf16x8*)(xbf + (size_t)s3 * DD + 8 * ll);
#pragma unroll
            for (int j = 0; j < 8; ++j) { B0[j] += bf2f(v2[j]); B1[j] += bf2f(v3[j]); }
            f += 8;
        }
        if (f < eB) {
            int s2 = ep[f];
            bf16x8 v2 = *(const bf16x8*)(xbf + (size_t)s2 * DD + 8 * ll);
#pragma unroll
            for (int j = 0; j < 8; ++j) B0[j] += bf2f(v2[j]);
        }
#pragma unroll
        for (int j = 0; j < 8; ++j) {
            float sA = A0[j] + A1[j];
            sA += __shfl_xor(sA, 16, 64);
            sA += __shfl_xor(sA, 32, 64);
            A0[j] = sA;
            float sB = B0[j] + B1[j];
            sB += __shfl_xor(sB, 16, 64);
            sB += __shfl_xor(sB, 32, 64);
            B0[j] = sB;
        }
        if (l == 0) { sdeg[m0] = dA; sdeg[m1] = dB; }
        if (qw == 0) {
            float invA = dA > 0 ? 1.f / (float)dA : 0.f;
            float invB = dB > 0 ? 1.f / (float)dB : 0.f;
            bf16x8 tA, tB;
#pragma unroll
            for (int j = 0; j < 8; ++j) { tA[j] = f2bf(A0[j] * invA); tB[j] = f2bf(B0[j] * invB); }
            *(bf16x8*)&agg_t[m0 * DD + ((8 * ll) ^ ((m0 & 7) << 3))] = tA;
            *(bf16x8*)&agg_t[m1 * DD + ((8 * ll) ^ ((m1 & 7) << 3))] = tB;
        }
    }
    __syncthreads();

    // ---- MFMA phase: wave = 16 rows (pair) x 64 cols (half) ----
    const int p = wu >> 1;
    const int half = wu & 1;
    f32x4 acc[4];
#pragma unroll
    for (int nb = 0; nb < 4; ++nb) acc[nb] = f32x4{0.f, 0.f, 0.f, 0.f};
    const int mrow = p * 16 + (l & 15);
    const int kg = (l >> 4) * 8;
    const int nloc = l & 15;
    const int groot = min(base + mrow, N_NODES - 1);
#pragma unroll
    for (int ks = 0; ks < 4; ++ks) {
        int kk = ks * 32 + kg;
        int sw = kk ^ ((mrow & 7) << 3);
        bf16x8 aa = *(const bf16x8*)&agg_t[mrow * DD + sw];
        bf16x8 ax = *(const bf16x8*)(xbf + (size_t)groot * DD + kk);
#pragma unroll
        for (int nb = 0; nb < 4; ++nb) {
            int n = half * 64 + nb * 16 + nloc;
            bf16x8 bl = *(const bf16x8*)&wl[n * DD + kk];
            bf16x8 br = *(const bf16x8*)&wr[n * DD + kk];
            acc[nb] = __builtin_amdgcn_mfma_f32_16x16x32_bf16(aa, bl, acc[nb], 0, 0, 0);
            acc[nb] = __builtin_amdgcn_mfma_f32_16x16x32_bf16(ax, br, acc[nb], 0, 0, 0);
        }
    }
    __syncthreads();   // agg tile reads done by both waves of every pair

    // ---- epilogue: bias, ELU, stats, C tile into LDS ----
    int degf[4];
#pragma unroll
    for (int r = 0; r < 4; ++r) degf[r] = sdeg[p * 16 + (l >> 4) * 4 + r];

    float colS[4], colQ[4];
#pragma unroll
    for (int nb = 0; nb < 4; ++nb) {
        int n = half * 64 + nb * 16 + nloc;
        float bb = bias_base[n];
        float bd = bias_deg[n];
        float cs = 0.f, cq = 0.f;
#pragma unroll
        for (int r = 0; r < 4; ++r) {
            int m = p * 16 + (l >> 4) * 4 + r;
            int g = base + m;
            float hv = acc[nb][r] + bb + (degf[r] > 0 ? bd : 0.f);
            if (ELU_ON) hv = hv > 0.f ? hv : expm1f(hv);
            agg_t[m * DD + (n ^ ((m & 7) << 3))] = f2bf(hv);
            float hm = (g < N_NODES) ? hv : 0.f;
            cs += hm;
            cq += hm * hm;
        }
        colS[nb] = cs; colQ[nb] = cq;
    }
#pragma unroll
    for (int nb = 0; nb < 4; ++nb) {
        colS[nb] += __shfl_xor(colS[nb], 16, 64);
        colS[nb] += __shfl_xor(colS[nb], 32, 64);
        colQ[nb] += __shfl_xor(colQ[nb], 16, 64);
        colQ[nb] += __shfl_xor(colQ[nb], 32, 64);
    }
    if (l < 16) {
#pragma unroll
        for (int nb = 0; nb < 4; ++nb) {
            sstat[wu * 128 + nb * 16 + l]      = colS[nb];
            sstat[wu * 128 + 64 + nb * 16 + l] = colQ[nb];
        }
    }
    __syncthreads();

    // ---- coalesced C write-out + stats combine ----
#pragma unroll
    for (int k = 0; k < 2; ++k) {
        int idx = (k * 512 + tid) * 8;           // short index in 64x128 tile
        int m = idx >> 7, c = idx & 127;
        int g = base + m;
        if (g < N_NODES) {
            bf16x8 v = *(const bf16x8*)&agg_t[m * DD + (c ^ ((m & 7) << 3))];
            *(bf16x8*)&hout[(size_t)g * DD + c] = v;
        }
    }
    if (tid < 256) {
        int f = tid & 127;
        int part = tid >> 7;                     // 0 = sum, 1 = sumsq
        int hsel = f >> 6;                       // which col-half wave
        int cw = part * 64 + (f & 63);
        float v = 0.f;
#pragma unroll
        for (int pr = 0; pr < 4; ++pr) v += sstat[(2 * pr + hsel) * 128 + cw];
        partials[blockIdx.x * 256 + tid] = v;
    }
}

// ---------------- BN stats -> affine ----------------
__global__ void k_reduce(const float* __restrict__ partials,
                         const float* __restrict__ gamma, const float* __restrict__ beta,
                         float* __restrict__ aff) {
    int f = blockIdx.x;     // 0..127
    int t = threadIdx.x;    // 256
    float s = 0.f, q = 0.f;
    for (int i = t; i < NBLK; i += 256) {
        s += partials[i * 256 + f];
        q += partials[i * 256 + 128 + f];
    }
    __shared__ float rs[256], rq[256];
    rs[t] = s; rq[t] = q;
    __syncthreads();
    for (int d = 128; d > 0; d >>= 1) {
        if (t < d) { rs[t] += rs[t + d]; rq[t] += rq[t + d]; }
        __syncthreads();
    }
    if (t == 0) {
        float mean = rs[0] / (float)N_NODES;
        float var = rq[0] / (float)N_NODES - mean * mean;
        float a = gamma[f] * rsqrtf(var + EPSV);
        aff[f] = a;
        aff[128 + f] = beta[f] - mean * a;
    }
}

// ---------------- final BN apply: bf16 h2 -> fp32 out ----------------
__global__ void k_apply(const short* __restrict__ hin, const float* __restrict__ aff,
                        float* __restrict__ out) {
    int i = blockIdx.x * 256 + threadIdx.x;  // bf16x8 units
    if (i < N_NODES * DD / 8) {
        bf16x8 v = *(const bf16x8*)(hin + (size_t)i * 8);
        int f = (i * 8) & 127;
        f32x4 a0 = *(const f32x4*)(aff + f);
        f32x4 a1 = *(const f32x4*)(aff + f + 4);
        f32x4 c0 = *(const f32x4*)(aff + 128 + f);
        f32x4 c1 = *(const f32x4*)(aff + 128 + f + 4);
        f32x4 o0, o1;
        o0.x = bf2f(v[0]) * a0.x + c0.x; o0.y = bf2f(v[1]) * a0.y + c0.y;
        o0.z = bf2f(v[2]) * a0.z + c0.z; o0.w = bf2f(v[3]) * a0.w + c0.w;
        o1.x = bf2f(v[4]) * a1.x + c1.x; o1.y = bf2f(v[5]) * a1.y + c1.y;
        o1.z = bf2f(v[6]) * a1.z + c1.z; o1.w = bf2f(v[7]) * a1.w + c1.w;
        *(f32x4*)(out + (size_t)i * 8) = o0;
        *(f32x4*)(out + (size_t)i * 8 + 4) = o1;
    }
}

extern "C" void kernel_launch(void* const* d_in, const int* in_sizes, int n_in,
                              void* d_out, int out_size, void* d_ws, size_t ws_size,
                              hipStream_t stream) {
    const float* x     = (const float*)d_in[0];
    const int*   ei    = (const int*)d_in[1];
    const float* Wl    = (const float*)d_in[2];
    const float* Wr    = (const float*)d_in[3];
    const float* b     = (const float*)d_in[4];
    const float* gamma = (const float*)d_in[5];
    const float* beta  = (const float*)d_in[6];
    float* out = (float*)d_out;

    char* ws = (char*)d_ws;
    int*   off      = (int*)(ws + 0);              // (N+1) ints
    int*   cnt      = (int*)(ws + 400128);         // N ints (count, then cursor)
    int*   elist    = (int*)(ws + 800256);         // E ints
    int*   bsums    = (int*)(ws + 4000256);        // 512 ints
    float* partials = (float*)(ws + 4002304);      // NBLK*256 floats (1.6MB)
    float* affine   = (float*)(ws + 5603840);      // 256 floats
    short* wbl      = (short*)(ws + 5604864);      // 128*128 bf16 folded
    short* wbr      = (short*)(ws + 5637632);      // 128*128 bf16 folded
    float* biasb    = (float*)(ws + 5670400);      // 128 floats
    float* biasd    = (float*)(ws + 5670912);      // 128 floats
    short* bufA     = (short*)(ws + 5671424);      // N*D bf16: xbf, then h1
    short* bufB     = (short*)(ws + 31271424);     // N*D bf16: h0, then h2

    const int* src = ei;
    const int* dst = ei + N_EDGES;

    // CSR build + x->bf16
    hipMemsetAsync(cnt, 0, N_NODES * sizeof(int), stream);
    k_setup<<<(N_NODES * DD / 8 + 255) / 256, 256, 0, stream>>>(x, bufA, dst, cnt);
    k_scan1<<<NSCAN1, 256, 0, stream>>>(cnt, off, bsums);
    k_scan2<<<1, 512, 0, stream>>>(bsums);
    k_scan3<<<NSCAN1, 256, 0, stream>>>(off, bsums);
    k_fill<<<(N_EDGES + 255) / 256, 256, 0, stream>>>(src, dst, off, cnt, elist);

    // layer 0: xbf(bufA) -> h0 (bufB), ELU, identity affine
    k_fold<<<128, 128, 0, stream>>>(Wl, Wr, b, affine, 0, wbl, wbr, biasb, biasd);
    k_sage<true><<<NBLK, 512, 0, stream>>>(bufA, off, elist, wbl, wbr,
                                           biasb, biasd, bufB, partials);
    k_reduce<<<128, 256, 0, stream>>>(partials, gamma, beta, affine);

    // layer 1: h0(bufB) -> h1 (bufA), ELU, affine folded
    k_fold<<<128, 128, 0, stream>>>(Wl + DD * DD, Wr + DD * DD, b + DD, affine, 1,
                                    wbl, wbr, biasb, biasd);
    k_sage<true><<<NBLK, 512, 0, stream>>>(bufB, off, elist, wbl, wbr,
                                           biasb, biasd, bufA, partials);
    k_reduce<<<128, 256, 0, stream>>>(partials, gamma + DD, beta + DD, affine);

    // layer 2: h1(bufA) -> h2 (bufB), no ELU, affine folded
    k_fold<<<128, 128, 0, stream>>>(Wl + 2 * DD * DD, Wr + 2 * DD * DD, b + 2 * DD,
                                    affine, 1, wbl, wbr, biasb, biasd);
    k_sage<false><<<NBLK, 512, 0, stream>>>(bufA, off, elist, wbl, wbr,
                                            biasb, biasd, bufB, partials);
    k_reduce<<<128, 256, 0, stream>>>(partials, gamma + 2 * DD, beta + 2 * DD, affine);

    // final BN apply: bf16 h2 -> fp32 out
    k_apply<<<(N_NODES * DD / 8 + 255) / 256, 256, 0, stream>>>(bufB, affine, out);
}

// Round 5
// 408.200 us; speedup vs baseline: 2.1272x; 1.0253x over previous
//
#include <hip/hip_runtime.h>
#include <hip/hip_bf16.h>

#define N_NODES 100000
#define N_EDGES 800000
#define DD 128
#define TILE 32
#define NBLK 3125         // ceil(N_NODES / 32)
#define NSCAN1 391        // ceil(N_NODES / 256)
#define EPSV 1e-5f
#define ECAP 768          // staged edge-index capacity per 32-node tile (mean 256)

typedef short bf16x8 __attribute__((ext_vector_type(8)));
typedef float f32x4 __attribute__((ext_vector_type(4)));

__device__ __forceinline__ short f2bf(float f) {
    unsigned u = __float_as_uint(f);
    unsigned r = (u + 0x7fffu + ((u >> 16) & 1u)) >> 16;  // RNE
    return (short)r;
}
__device__ __forceinline__ float bf2f(short s) {
    return __uint_as_float(((unsigned)(unsigned short)s) << 16);
}

// ---------------- setup: x fp32->bf16 fused with degree count ----------------
__global__ void k_setup(const float* __restrict__ x, short* __restrict__ xbf,
                        const int* __restrict__ dst, int* __restrict__ cnt) {
    int i = blockIdx.x * 256 + threadIdx.x;
    if (i < N_NODES * DD / 8) {
        f32x4 v0 = *(const f32x4*)(x + (size_t)i * 8);
        f32x4 v1 = *(const f32x4*)(x + (size_t)i * 8 + 4);
        bf16x8 t;
        t[0] = f2bf(v0.x); t[1] = f2bf(v0.y); t[2] = f2bf(v0.z); t[3] = f2bf(v0.w);
        t[4] = f2bf(v1.x); t[5] = f2bf(v1.y); t[6] = f2bf(v1.z); t[7] = f2bf(v1.w);
        *(bf16x8*)&xbf[(size_t)i * 8] = t;
    }
    if (i < N_EDGES) atomicAdd(&cnt[dst[i]], 1);
}

// ---------------- CSR build ----------------
__global__ void k_scan1(const int* __restrict__ cnt, int* __restrict__ off,
                        int* __restrict__ bsums) {
    __shared__ int s[256];
    int i = blockIdx.x * 256 + threadIdx.x;
    int t = threadIdx.x;
    s[t] = (i < N_NODES) ? cnt[i] : 0;
    __syncthreads();
    for (int d = 1; d < 256; d <<= 1) {
        int x = 0;
        if (t >= d) x = s[t - d];
        __syncthreads();
        s[t] += x;
        __syncthreads();
    }
    if (i < N_NODES) off[i + 1] = s[t];
    if (t == 255) bsums[blockIdx.x] = s[255];
}

__global__ void k_scan2(int* __restrict__ bsums) {
    __shared__ int s[512];
    int t = threadIdx.x;
    s[t] = (t < NSCAN1) ? bsums[t] : 0;
    __syncthreads();
    for (int d = 1; d < 512; d <<= 1) {
        int x = 0;
        if (t >= d) x = s[t - d];
        __syncthreads();
        s[t] += x;
        __syncthreads();
    }
    if (t < NSCAN1) bsums[t] = s[t];   // inclusive
}

__global__ void k_scan3(int* __restrict__ off, const int* __restrict__ bsums) {
    int i = blockIdx.x * 256 + threadIdx.x;
    int add = (blockIdx.x > 0) ? bsums[blockIdx.x - 1] : 0;
    if (i < N_NODES) off[i + 1] += add;
    if (i == 0) off[0] = 0;
}

// uses cnt (still holding counts) as a down-counter: no second memset needed
__global__ void k_fill(const int* __restrict__ src, const int* __restrict__ dst,
                       const int* __restrict__ off, int* __restrict__ cur,
                       int* __restrict__ elist) {
    int e = blockIdx.x * 256 + threadIdx.x;
    if (e < N_EDGES) {
        int d = dst[e];
        int p = atomicSub(&cur[d], 1);   // old value >= 1
        elist[off[d] + p - 1] = src[e];
    }
}

// ---------------- fold BN affine into weights/bias ----------------
__global__ void k_fold(const float* __restrict__ wl, const float* __restrict__ wr,
                       const float* __restrict__ b, const float* __restrict__ aff,
                       int use_aff,
                       short* __restrict__ wblo, short* __restrict__ wbro,
                       float* __restrict__ bias_base, float* __restrict__ bias_deg) {
    int o = blockIdx.x;     // 0..127
    int k = threadIdx.x;    // 0..127
    float a = use_aff ? aff[k] : 1.f;
    float c = use_aff ? aff[128 + k] : 0.f;
    float vl = wl[o * DD + k], vr = wr[o * DD + k];
    wblo[o * DD + k] = f2bf(vl * a);
    wbro[o * DD + k] = f2bf(vr * a);
    __shared__ float s1[128], s2[128];
    s1[k] = c * vr; s2[k] = c * vl;
    __syncthreads();
    for (int d = 64; d > 0; d >>= 1) {
        if (k < d) { s1[k] += s1[k + d]; s2[k] += s2[k + d]; }
        __syncthreads();
    }
    if (k == 0) {
        bias_base[o] = b[o] + s1[0];
        bias_deg[o] = s2[0];
    }
}

// ---------------- fused SAGE layer ----------------
// 32-node tile, 256 threads (4 waves).
// Gather: quarter-wave OWNS one row (16 lanes x 16B = 256B row); each lane
// privately accumulates its 8 features -> no shuffle reduce. Software-
// pipelined 2-deep edge walk keeps loads in flight under the VALU adds.
// MFMA: wave pair shares a 16-row tile, each wave one 64-col half.
template <bool ELU_ON>
__global__ __launch_bounds__(256, 6) void k_sage(
    const short* __restrict__ xbf,
    const int* __restrict__ off, const int* __restrict__ elist,
    const short* __restrict__ wl, const short* __restrict__ wr,
    const float* __restrict__ bias_base, const float* __restrict__ bias_deg,
    short* __restrict__ hout, float* __restrict__ partials)
{
    __shared__ short agg_t[TILE * 128];   // 8KB: agg tile, then reused as C tile
    __shared__ int sdeg[TILE];
    __shared__ float sstat[4 * 128];      // per-wave column stats staging
    __shared__ int soff[TILE + 1];
    __shared__ int eidx[ECAP];
    const int tid = threadIdx.x;
    const int wu = __builtin_amdgcn_readfirstlane(tid >> 6);
    const int l = tid & 63;
    const int base = blockIdx.x * TILE;
    const int qw = l >> 4;        // quarter-wave 0..3 = row within quad
    const int ll = l & 15;        // lane in quarter-wave: cols 8*ll..8*ll+7

    // ---- stage offsets + edge indices into LDS ----
    if (tid < TILE + 1) soff[tid] = off[min(base + tid, N_NODES)];
    __syncthreads();
    const int ebase = soff[0];
    const int etot = soff[TILE] - ebase;
    const bool ovf = etot > ECAP;
    for (int k = tid; k < (ovf ? 0 : etot); k += 256) eidx[k] = elist[ebase + k];
    __syncthreads();
    const int* ep = ovf ? (elist + ebase) : (const int*)eidx;

    // ---- gather: each wave owns rows wu*8..wu*8+7 as 2 quads of 4 ----
#pragma unroll
    for (int q = 0; q < 2; ++q) {
        const int m = wu * 8 + q * 4 + qw;      // this quarter-wave's row
        const int ea = soff[m] - ebase;
        const int eA = soff[m + 1] - ebase;
        const int deg = eA - ea;
        float acc[8];
#pragma unroll
        for (int j = 0; j < 8; ++j) acc[j] = 0.f;

        int e = ea;
        bool val0 = e < eA, val1 = e + 1 < eA;
        bf16x8 v0{}, v1{};
        if (val0) v0 = *(const bf16x8*)(xbf + (size_t)ep[e] * DD + 8 * ll);
        if (val1) v1 = *(const bf16x8*)(xbf + (size_t)ep[e + 1] * DD + 8 * ll);
        while (__any((int)(val0 || val1))) {
            int en = e + 2;
            bool nv0 = en < eA, nv1 = en + 1 < eA;
            bf16x8 w0{}, w1{};
            if (nv0) w0 = *(const bf16x8*)(xbf + (size_t)ep[en] * DD + 8 * ll);
            if (nv1) w1 = *(const bf16x8*)(xbf + (size_t)ep[en + 1] * DD + 8 * ll);
            if (val0) {
#pragma unroll
                for (int j = 0; j < 8; ++j) acc[j] += bf2f(v0[j]);
            }
            if (val1) {
#pragma unroll
                for (int j = 0; j < 8; ++j) acc[j] += bf2f(v1[j]);
            }
            v0 = w0; v1 = w1; val0 = nv0; val1 = nv1; e = en;
        }

        float inv = deg > 0 ? 1.f / (float)deg : 0.f;
        bf16x8 t;
#pragma unroll
        for (int j = 0; j < 8; ++j) t[j] = f2bf(acc[j] * inv);
        *(bf16x8*)&agg_t[m * DD + ((8 * ll) ^ ((m & 7) << 3))] = t;
        if (ll == 0) sdeg[m] = deg;
    }
    __syncthreads();

    // ---- MFMA phase: wave = 16 rows (pair) x 64 cols (half) ----
    const int p = wu >> 1;
    const int half = wu & 1;
    f32x4 acc[4];
#pragma unroll
    for (int nb = 0; nb < 4; ++nb) acc[nb] = f32x4{0.f, 0.f, 0.f, 0.f};
    const int mrow = p * 16 + (l & 15);
    const int kg = (l >> 4) * 8;
    const int nloc = l & 15;
    const int groot = min(base + mrow, N_NODES - 1);
#pragma unroll
    for (int ks = 0; ks < 4; ++ks) {
        int kk = ks * 32 + kg;
        int sw = kk ^ ((mrow & 7) << 3);
        bf16x8 aa = *(const bf16x8*)&agg_t[mrow * DD + sw];
        bf16x8 ax = *(const bf16x8*)(xbf + (size_t)groot * DD + kk);
#pragma unroll
        for (int nb = 0; nb < 4; ++nb) {
            int n = half * 64 + nb * 16 + nloc;
            bf16x8 bl = *(const bf16x8*)&wl[n * DD + kk];
            bf16x8 br = *(const bf16x8*)&wr[n * DD + kk];
            acc[nb] = __builtin_amdgcn_mfma_f32_16x16x32_bf16(aa, bl, acc[nb], 0, 0, 0);
            acc[nb] = __builtin_amdgcn_mfma_f32_16x16x32_bf16(ax, br, acc[nb], 0, 0, 0);
        }
    }
    __syncthreads();   // agg tile reads done by both waves of every pair

    // ---- epilogue: bias, ELU, stats, C tile into LDS ----
    int degf[4];
#pragma unroll
    for (int r = 0; r < 4; ++r) degf[r] = sdeg[p * 16 + (l >> 4) * 4 + r];

    float colS[4], colQ[4];
#pragma unroll
    for (int nb = 0; nb < 4; ++nb) {
        int n = half * 64 + nb * 16 + nloc;
        float bb = bias_base[n];
        float bd = bias_deg[n];
        float cs = 0.f, cq = 0.f;
#pragma unroll
        for (int r = 0; r < 4; ++r) {
            int m = p * 16 + (l >> 4) * 4 + r;
            int g = base + m;
            float hv = acc[nb][r] + bb + (degf[r] > 0 ? bd : 0.f);
            if (ELU_ON) hv = hv > 0.f ? hv : expm1f(hv);
            agg_t[m * DD + (n ^ ((m & 7) << 3))] = f2bf(hv);
            float hm = (g < N_NODES) ? hv : 0.f;
            cs += hm;
            cq += hm * hm;
        }
        colS[nb] = cs; colQ[nb] = cq;
    }
#pragma unroll
    for (int nb = 0; nb < 4; ++nb) {
        colS[nb] += __shfl_xor(colS[nb], 16, 64);
        colS[nb] += __shfl_xor(colS[nb], 32, 64);
        colQ[nb] += __shfl_xor(colQ[nb], 16, 64);
        colQ[nb] += __shfl_xor(colQ[nb], 32, 64);
    }
    if (l < 16) {
#pragma unroll
        for (int nb = 0; nb < 4; ++nb) {
            sstat[wu * 128 + nb * 16 + l]      = colS[nb];
            sstat[wu * 128 + 64 + nb * 16 + l] = colQ[nb];
        }
    }
    __syncthreads();

    // ---- coalesced C write-out + stats combine ----
#pragma unroll
    for (int k = 0; k < 2; ++k) {
        int idx = (k * 256 + tid) * 8;           // short index in 32x128 tile
        int m = idx >> 7, c = idx & 127;
        int g = base + m;
        if (g < N_NODES) {
            bf16x8 v = *(const bf16x8*)&agg_t[m * DD + (c ^ ((m & 7) << 3))];
            *(bf16x8*)&hout[(size_t)g * DD + c] = v;
        }
    }
    {
        int f = tid & 127;
        int part = tid >> 7;                     // 0 = sum, 1 = sumsq
        int hsel = f >> 6;                       // which col-half wave
        int cw = part * 64 + (f & 63);
        float v = 0.f;
#pragma unroll
        for (int pr = 0; pr < 2; ++pr) v += sstat[(2 * pr + hsel) * 128 + cw];
        partials[blockIdx.x * 256 + tid] = v;
    }
}

// ---------------- BN stats -> affine ----------------
__global__ void k_reduce(const float* __restrict__ partials,
                         const float* __restrict__ gamma, const float* __restrict__ beta,
                         float* __restrict__ aff) {
    int f = blockIdx.x;     // 0..127
    int t = threadIdx.x;    // 256
    float s = 0.f, q = 0.f;
    for (int i = t; i < NBLK; i += 256) {
        s += partials[i * 256 + f];
        q += partials[i * 256 + 128 + f];
    }
    __shared__ float rs[256], rq[256];
    rs[t] = s; rq[t] = q;
    __syncthreads();
    for (int d = 128; d > 0; d >>= 1) {
        if (t < d) { rs[t] += rs[t + d]; rq[t] += rq[t + d]; }
        __syncthreads();
    }
    if (t == 0) {
        float mean = rs[0] / (float)N_NODES;
        float var = rq[0] / (float)N_NODES - mean * mean;
        float a = gamma[f] * rsqrtf(var + EPSV);
        aff[f] = a;
        aff[128 + f] = beta[f] - mean * a;
    }
}

// ---------------- final BN apply: bf16 h2 -> fp32 out ----------------
__global__ void k_apply(const short* __restrict__ hin, const float* __restrict__ aff,
                        float* __restrict__ out) {
    int i = blockIdx.x * 256 + threadIdx.x;  // bf16x8 units
    if (i < N_NODES * DD / 8) {
        bf16x8 v = *(const bf16x8*)(hin + (size_t)i * 8);
        int f = (i * 8) & 127;
        f32x4 a0 = *(const f32x4*)(aff + f);
        f32x4 a1 = *(const f32x4*)(aff + f + 4);
        f32x4 c0 = *(const f32x4*)(aff + 128 + f);
        f32x4 c1 = *(const f32x4*)(aff + 128 + f + 4);
        f32x4 o0, o1;
        o0.x = bf2f(v[0]) * a0.x + c0.x; o0.y = bf2f(v[1]) * a0.y + c0.y;
        o0.z = bf2f(v[2]) * a0.z + c0.z; o0.w = bf2f(v[3]) * a0.w + c0.w;
        o1.x = bf2f(v[4]) * a1.x + c1.x; o1.y = bf2f(v[5]) * a1.y + c1.y;
        o1.z = bf2f(v[6]) * a1.z + c1.z; o1.w = bf2f(v[7]) * a1.w + c1.w;
        *(f32x4*)(out + (size_t)i * 8) = o0;
        *(f32x4*)(out + (size_t)i * 8 + 4) = o1;
    }
}

extern "C" void kernel_launch(void* const* d_in, const int* in_sizes, int n_in,
                              void* d_out, int out_size, void* d_ws, size_t ws_size,
                              hipStream_t stream) {
    const float* x     = (const float*)d_in[0];
    const int*   ei    = (const int*)d_in[1];
    const float* Wl    = (const float*)d_in[2];
    const float* Wr    = (const float*)d_in[3];
    const float* b     = (const float*)d_in[4];
    const float* gamma = (const float*)d_in[5];
    const float* beta  = (const float*)d_in[6];
    float* out = (float*)d_out;

    char* ws = (char*)d_ws;
    int*   off      = (int*)(ws + 0);              // (N+1) ints
    int*   cnt      = (int*)(ws + 400128);         // N ints (count, then cursor)
    int*   elist    = (int*)(ws + 800256);         // E ints
    int*   bsums    = (int*)(ws + 4000256);        // 512 ints
    float* partials = (float*)(ws + 4002304);      // NBLK*256 floats (3.2MB)
    float* affine   = (float*)(ws + 7202304);      // 256 floats
    short* wbl      = (short*)(ws + 7203328);      // 128*128 bf16 folded
    short* wbr      = (short*)(ws + 7236096);      // 128*128 bf16 folded
    float* biasb    = (float*)(ws + 7268864);      // 128 floats
    float* biasd    = (float*)(ws + 7269376);      // 128 floats
    short* bufA     = (short*)(ws + 7269888);      // N*D bf16: xbf, then h1
    short* bufB     = (short*)(ws + 32869888);     // N*D bf16: h0, then h2

    const int* src = ei;
    const int* dst = ei + N_EDGES;

    // CSR build + x->bf16
    hipMemsetAsync(cnt, 0, N_NODES * sizeof(int), stream);
    k_setup<<<(N_NODES * DD / 8 + 255) / 256, 256, 0, stream>>>(x, bufA, dst, cnt);
    k_scan1<<<NSCAN1, 256, 0, stream>>>(cnt, off, bsums);
    k_scan2<<<1, 512, 0, stream>>>(bsums);
    k_scan3<<<NSCAN1, 256, 0, stream>>>(off, bsums);
    k_fill<<<(N_EDGES + 255) / 256, 256, 0, stream>>>(src, dst, off, cnt, elist);

    // layer 0: xbf(bufA) -> h0 (bufB), ELU, identity affine
    k_fold<<<128, 128, 0, stream>>>(Wl, Wr, b, affine, 0, wbl, wbr, biasb, biasd);
    k_sage<true><<<NBLK, 256, 0, stream>>>(bufA, off, elist, wbl, wbr,
                                           biasb, biasd, bufB, partials);
    k_reduce<<<128, 256, 0, stream>>>(partials, gamma, beta, affine);

    // layer 1: h0(bufB) -> h1 (bufA), ELU, affine folded
    k_fold<<<128, 128, 0, stream>>>(Wl + DD * DD, Wr + DD * DD, b + DD, affine, 1,
                                    wbl, wbr, biasb, biasd);
    k_sage<true><<<NBLK, 256, 0, stream>>>(bufB, off, elist, wbl, wbr,
                                           biasb, biasd, bufA, partials);
    k_reduce<<<128, 256, 0, stream>>>(partials, gamma + DD, beta + DD, affine);

    // layer 2: h1(bufA) -> h2 (bufB), no ELU, affine folded
    k_fold<<<128, 128, 0, stream>>>(Wl + 2 * DD * DD, Wr + 2 * DD * DD, b + 2 * DD,
                                    affine, 1, wbl, wbr, biasb, biasd);
    k_sage<false><<<NBLK, 256, 0, stream>>>(bufA, off, elist, wbl, wbr,
                                            biasb, biasd, bufB, partials);
    k_reduce<<<128, 256, 0, stream>>>(partials, gamma + 2 * DD, beta + 2 * DD, affine);

    // final BN apply: bf16 h2 -> fp32 out
    k_apply<<<(N_NODES * DD / 8 + 255) / 256, 256, 0, stream>>>(bufB, affine, out);
}